// Round 8
// baseline (836.708 us; speedup 1.0000x reference)
//
#include <hip/hip_runtime.h>

#define BB 128
#define TT 1024
#define DD 256
#define UU 64

// Single-wave LDS ordering fence (fallback path only).
#define WAVE_LDS_FENCE() asm volatile("s_waitcnt lgkmcnt(0)" ::: "memory")

// ---------------- pot = x @ W + b + boundaries ----------------
// v5: lane = ROW (not column). Old v4 was DS-pipe-bound: 256 uniform-
// broadcast ds_read_b128 per kt per wave for 1024 FMAs (broadcast still
// retires 1024B/inst to the RF). Now each lane owns one x-row: per kt a
// wave does 16 per-lane ds_read_b128 (all 1024B useful -> 16x fewer DS
// insts) and 4096 FMAs; W rows are wave-uniform scalar loads (W = 64KB,
// reused by every block -> sKcache/L2 hot). One wave per block; x staged
// HBM->LDS by global_load_lds with XOR-swizzled SOURCE (LDS chunk c of
// row r holds global chunk c^(r&15)) so the per-lane column-slice reads
// are ~8-way instead of 64-way bank-conflicted (rule: swizzle both sides
// or neither; DMA dest must stay linear).
// Bit-exact: acc[u] accumulates d = kt*64 + j*4 + k ascending 0..255 —
// identical FMA chain as the verified kernel; epilogue +b,+left,+right
// order unchanged; LDS round-trip preserves bits.
__global__ __launch_bounds__(64) void pot_kernel(
    const float* __restrict__ x, const float* __restrict__ W,
    const float* __restrict__ bvec, const float* __restrict__ left,
    const float* __restrict__ right, const int* __restrict__ lengths,
    float* __restrict__ pot)
{
  const int lane = threadIdx.x;               // local row 0..63
  const int rowblk = (int)blockIdx.x * 64;
  const int row = rowblk + lane;

  __shared__ __align__(16) float xs[64][64];  // 16 KB, single buffer

  // DMA lane mapping for inst q: row r = 4q + (lane>>4), LDS chunk
  // (lane&15) <- global chunk (lane&15) ^ (r&15).
  const int sr4 = lane >> 4;                  // 0..3
  const int scl = lane & 15;                  // 0..15

  float acc[64];
#pragma unroll
  for (int u = 0; u < 64; ++u) acc[u] = 0.f;

#pragma unroll 1
  for (int kt = 0; kt < 4; ++kt) {
    // ---- stage kt tile (16 DMA insts, zero data registers) ----
#pragma unroll
    for (int q = 0; q < 16; ++q) {
      const int r = q * 4 + sr4;
      const int cG = scl ^ (r & 15);
      const float* gp = x + (size_t)(rowblk + r) * DD + kt * 64 + cG * 4;
      float* lp = &xs[q * 4][0];              // wave-uniform base + lane*16
      __builtin_amdgcn_global_load_lds(
          (const __attribute__((address_space(1))) void*)gp,
          (__attribute__((address_space(3))) void*)lp, 16, 0, 0);
    }
    asm volatile("s_waitcnt vmcnt(0)" ::: "memory");
    __builtin_amdgcn_sched_barrier(0);

    // ---- compute: per lane, its row x uniform W rows ----
#pragma unroll 1
    for (int j = 0; j < 16; ++j) {
      const float4 xv =
          *(const float4*)&xs[lane][(j ^ scl) * 4];   // = x[row][kt*64+4j..+3]
      const float* wr0 = W + (size_t)(kt * 64 + j * 4) * UU;  // uniform
#pragma unroll
      for (int k = 0; k < 4; ++k) {
        const float xd = (k == 0) ? xv.x : (k == 1) ? xv.y : (k == 2) ? xv.z : xv.w;
        const float* wr = wr0 + k * UU;       // uniform -> s_load path
#pragma unroll
        for (int u = 0; u < 64; ++u)
          acc[u] = fmaf(xd, wr[u], acc[u]);
      }
    }
    // all ds_reads consumed before next kt's DMA overwrites the buffer
    WAVE_LDS_FENCE();
  }

  // ---- epilogue: +b, boundaries, coalesced-per-lane dwordx4 stores ----
  const int bidx = row >> 10;                 // wave-uniform (64-row tiles)
  const int t = row & (TT - 1);               // per-lane
  const int len = lengths[bidx];
  const bool isf = (t == 0);
  const bool isl = (t == len - 1);
  float* pr = pot + (size_t)row * UU;
#pragma unroll
  for (int c = 0; c < 16; ++c) {
    float4 v4;
    float vv[4];
#pragma unroll
    for (int k = 0; k < 4; ++k) {
      const int u = c * 4 + k;
      float v = acc[u] + bvec[u];             // bvec[u] uniform scalar load
      if (isf) v += left[u];
      if (isl) v += right[u];
      vv[k] = v;
    }
    v4.x = vv[0]; v4.y = vv[1]; v4.z = vv[2]; v4.w = vv[3];
    *(float4*)(pr + c * 4) = v4;
  }
}

// ---------------- forward + viterbi scans ----------------
// 2*B one-wave blocks: [0,B) forward, [B,2B) viterbi. lane = state u.
// (unchanged from round 7 — verified; scan is cross-lane-throughput-bound,
// structural fix deferred.)
__global__ __launch_bounds__(64)
__attribute__((amdgpu_waves_per_eu(1, 1))) void scan_kernel(
    const float* __restrict__ pot, const float* __restrict__ trans,
    const int* __restrict__ lengths,
    unsigned char* __restrict__ bp, float* __restrict__ log_norm,
    int* __restrict__ last_tag, float* __restrict__ valpha, int fast)
{
  const int lane = threadIdx.x;
  const int b = blockIdx.x & (BB - 1);
  const bool is_vit = blockIdx.x >= BB;
  const int len = lengths[b];
  const float* potb = pot + (size_t)b * TT * UU;

  __shared__ __align__(16) float sh[2][64];   // fallback path only

#define RLF(au, v) __uint_as_float(__builtin_amdgcn_readlane((au), (v)))

  if (!is_vit) {
    // ---- scaled linear-domain forward
    float tE[64];
#pragma unroll
    for (int v = 0; v < 64; ++v)
      tE[v] = __expf(trans[v * UU + lane]);

    float A = __expf(potb[lane]);          // t = 0; pot ~ N(0,1), safe
    int C = 0;                             // accumulated exponent (ln2 units)

    // pexp ring (exp'd, feeds t+1..t+3) + raw ring (loads for t+3..t+6).
    float pe1 = __expf(potb[UU + lane]);
    float pe2 = __expf(potb[2 * UU + lane]);
    float pe3 = __expf(potb[3 * UU + lane]);
    float pr4 = potb[4 * UU + lane];
    float pr5 = potb[5 * UU + lane];
    float pr6 = potb[6 * UU + lane];
    float pr7 = potb[7 * UU + lane];

#pragma unroll 1
    for (int t = 1; t < len; ++t) {
      float pcur = pe1;
      pe1 = pe2; pe2 = pe3;
      pe3 = __expf(pr4);                   // load is 3 steps old: latency covered
      pr4 = pr5; pr5 = pr6; pr6 = pr7;
      int tp = t + 7 < TT ? t + 7 : TT - 1;
      pr7 = potb[(size_t)tp * UU + lane];

      const unsigned Au = __float_as_uint(A);
      float s0 = 0.f, s1 = 0.f, s2 = 0.f, s3 = 0.f;
#pragma unroll
      for (int vg = 0; vg < 4; ++vg) {
        float bc[16];
#pragma unroll
        for (int c = 0; c < 16; ++c)
          bc[c] = RLF(Au, vg * 16 + c);
        __builtin_amdgcn_sched_barrier(0);  // all 16 readlanes precede uses
#pragma unroll
        for (int c = 0; c < 4; ++c) {
          s0 = fmaf(bc[c],      tE[vg * 16 + 0 + c],  s0);
          s1 = fmaf(bc[4 + c],  tE[vg * 16 + 4 + c],  s1);
          s2 = fmaf(bc[8 + c],  tE[vg * 16 + 8 + c],  s2);
          s3 = fmaf(bc[12 + c], tE[vg * 16 + 12 + c], s3);
        }
      }
      float sum = (s0 + s1) + (s2 + s3);
      A = sum * pcur;
      if ((t & 3) == 0) {
        // uniform rescale by lane-0 exponent; all-lane values stay in range
        unsigned ab = __builtin_amdgcn_readfirstlane(__float_as_uint(A));
        int k = (int)((ab >> 23) & 0xffu) - 127;
        C += k;
        A = __builtin_ldexpf(A, -k);
      }
    }
    // log_norm[b] = log(sum_lanes A) + C*ln2
    float e = A;
#pragma unroll
    for (int off = 32; off > 0; off >>= 1)
      e += __shfl_xor(e, off);
    if (lane == 0) log_norm[b] = __logf(e) + (float)C * 0.69314718056f;
  } else {
    float tT[64];
#pragma unroll
    for (int v = 0; v < 64; ++v)
      tT[v] = trans[v * UU + lane];

    float va = potb[lane];

    if (fast) {
      // ---- max-only viterbi scan (batched readlane broadcast); alphas
      // stored for parallel bp recompute
      float* vab = valpha + (size_t)b * TT * UU;
      vab[lane] = va;                      // row 0 = pot[b,0,:]
      float pn1 = potb[UU + lane];
      float pn2 = potb[2 * UU + lane];
      float pn3 = potb[3 * UU + lane];
      float pn4 = potb[4 * UU + lane];

#pragma unroll 1
      for (int t = 1; t < len; ++t) {
        float pcur = pn1;
        pn1 = pn2; pn2 = pn3; pn3 = pn4;
        int tp = t + 4 < TT ? t + 4 : TT - 1;
        pn4 = potb[(size_t)tp * UU + lane];

        const unsigned Vu = __float_as_uint(va);
        float m0 = -3.4e38f, m1 = -3.4e38f, m2 = -3.4e38f, m3 = -3.4e38f;
#pragma unroll
        for (int vg = 0; vg < 4; ++vg) {
          float bc[16];
#pragma unroll
          for (int c = 0; c < 16; ++c)
            bc[c] = RLF(Vu, vg * 16 + c);
          __builtin_amdgcn_sched_barrier(0);
          m0 = fmaxf(fmaxf(fmaxf(fmaxf(
                   bc[0] + tT[vg * 16 + 0],
                   bc[1] + tT[vg * 16 + 1]),
                   bc[2] + tT[vg * 16 + 2]),
                   bc[3] + tT[vg * 16 + 3]), m0);
          m1 = fmaxf(fmaxf(fmaxf(fmaxf(
                   bc[4] + tT[vg * 16 + 4],
                   bc[5] + tT[vg * 16 + 5]),
                   bc[6] + tT[vg * 16 + 6]),
                   bc[7] + tT[vg * 16 + 7]), m1);
          m2 = fmaxf(fmaxf(fmaxf(fmaxf(
                   bc[8] + tT[vg * 16 + 8],
                   bc[9] + tT[vg * 16 + 9]),
                   bc[10] + tT[vg * 16 + 10]),
                   bc[11] + tT[vg * 16 + 11]), m2);
          m3 = fmaxf(fmaxf(fmaxf(fmaxf(
                   bc[12] + tT[vg * 16 + 12],
                   bc[13] + tT[vg * 16 + 13]),
                   bc[14] + tT[vg * 16 + 14]),
                   bc[15] + tT[vg * 16 + 15]), m3);
        }
        float m = fmaxf(fmaxf(m0, m1), fmaxf(m2, m3));
        va = m + pcur;
        vab[(size_t)t * UU + lane] = va;   // fire-and-forget, off-chain
      }
    } else {
      // ---- original in-scan argmax path (fallback for small workspace)
      float pn1 = potb[UU + lane];
      float pn2 = potb[2 * UU + lane];
      float pn3 = potb[3 * UU + lane];
      unsigned char* bpb = bp + (size_t)b * TT * UU;

#pragma unroll 1
      for (int t = 1; t < len; ++t) {
        const int p = t & 1;
        sh[p][lane] = va;
        float pcur = pn1;
        pn1 = pn2; pn2 = pn3;
        int tp = t + 3 < TT ? t + 3 : TT - 1;
        pn3 = potb[(size_t)tp * UU + lane];
        WAVE_LDS_FENCE();
        const float4* sh4 = (const float4*)sh[p];
        float mc[8];
        int ac[8];
#pragma unroll
        for (int c = 0; c < 8; ++c) {
          float m = -3.4e38f;
          int am = 0;
#pragma unroll
          for (int q = 0; q < 2; ++q) {
            float4 a4 = sh4[c * 2 + q];
            int base = c * 8 + q * 4;
            float s;
            s = a4.x + tT[base + 0]; if (s > m) { m = s; am = base + 0; }
            s = a4.y + tT[base + 1]; if (s > m) { m = s; am = base + 1; }
            s = a4.z + tT[base + 2]; if (s > m) { m = s; am = base + 2; }
            s = a4.w + tT[base + 3]; if (s > m) { m = s; am = base + 3; }
          }
          mc[c] = m; ac[c] = am;
        }
        float m = mc[0]; int am = ac[0];
#pragma unroll
        for (int c = 1; c < 8; ++c) {
          if (mc[c] > m) { m = mc[c]; am = ac[c]; }
        }
        va = m + pcur;
        bpb[(size_t)(t - 1) * UU + lane] = (unsigned char)am;
      }

      // identity backpointers for rows r in [len-1, TT-2]
      {
        const int off = lane * 4;          // 0..252
        const unsigned b0 = (unsigned)(off & 63);
        const unsigned pattern = b0 | ((b0 + 1) << 8) | ((b0 + 2) << 16) | ((b0 + 3) << 24);
#pragma unroll 1
        for (int r0 = len - 1; r0 < TT - 1; r0 += 4) {
          int row = r0 + (off >> 6);
          if (row < TT - 1)
            *(unsigned*)(bpb + (size_t)row * UU + (off & 63)) = pattern;
        }
      }
    }

    // last_tag[b] = argmax over lanes, first-index tie-break (np.argmax)
    float v = va;
    int idx = lane;
#pragma unroll
    for (int off = 32; off > 0; off >>= 1) {
      float vo = __shfl_down(v, off);
      int io = __shfl_down(idx, off);
      if (vo > v || (vo == v && io < idx)) { v = vo; idx = io; }
    }
    if (lane == 0) last_tag[b] = idx;
  }
#undef RLF
}

// ---------------- parallel backpointer recompute (fast path) ----------------
// v2: the valpha row is loaded with ONE coalesced per-lane vector load and
// broadcast via v_readlane — the old wave-uniform scalar-load version
// streamed 32 MB through the scalar cache (the round-2 anti-pattern).
// Bit-exact: same f32 adds on same bits, same ascending strict-> scan ->
// identical bp bytes. 32768 waves -> readlane cost hidden by TLP.
__global__ __launch_bounds__(256) void bp_kernel(
    const float* __restrict__ valpha, const float* __restrict__ trans,
    const int* __restrict__ lengths, unsigned char* __restrict__ bp)
{
  const int lane = threadIdx.x & 63;              // = u
  const int w = __builtin_amdgcn_readfirstlane((int)(threadIdx.x >> 6));
  const int b = blockIdx.x >> 6;                  // 64 blocks per batch elem
  const int rg = ((int)(blockIdx.x & 63)) * 16 + w * 4;
  const int len = lengths[b];

#define RLF(au, v) __uint_as_float(__builtin_amdgcn_readlane((au), (v)))

  float tcol[64];
#pragma unroll
  for (int v = 0; v < 64; ++v)
    tcol[v] = trans[v * UU + lane];

  unsigned char* bpb = bp + (size_t)b * TT * UU;
#pragma unroll
  for (int k = 0; k < 4; ++k) {
    int r = rg + k;
    if (r >= TT - 1) continue;
    if (r >= len - 1) {
      bpb[(size_t)r * UU + lane] = (unsigned char)lane;   // identity rows
    } else {
      const float* vr = valpha + ((size_t)b * TT + r) * UU;
      const unsigned avu = __float_as_uint(vr[lane]);     // coalesced load
      float m = RLF(avu, 0) + tcol[0];
      int am = 0;
#pragma unroll
      for (int v = 1; v < 64; ++v) {
        float s = RLF(avu, v) + tcol[v];
        if (s > m) { m = s; am = v; }
      }
      bpb[(size_t)r * UU + lane] = (unsigned char)am;
    }
  }
#undef RLF
}

// ---------------- gold score + backtrack + decode ----------------
__global__ __launch_bounds__(64)
__attribute__((amdgpu_waves_per_eu(1, 1))) void decode_kernel(
    const float* __restrict__ pot, const float* __restrict__ trans,
    const int* __restrict__ tags, const int* __restrict__ lengths,
    const unsigned char* __restrict__ bp, const float* __restrict__ log_norm,
    const int* __restrict__ last_tag, float* __restrict__ score,
    float* __restrict__ dec_out)
{
  const int lane = threadIdx.x;
  const int b = blockIdx.x;
  const int len = lengths[b];
  const float* potb = pot + (size_t)b * TT * UU;
  const int* tagb = tags + (size_t)b * TT;

  // gold path score (unary + binary over valid positions)
  float s = 0.f;
#pragma unroll 1
  for (int i = 0; i < TT / 64; ++i) {
    int t = i * 64 + lane;
    if (t < len) {
      int tg = tagb[t];
      s += potb[(size_t)t * UU + tg];
      if (t > 0) s += trans[tagb[t - 1] * UU + tg];
    }
  }
#pragma unroll
  for (int off = 32; off > 0; off >>= 1)
    s += __shfl_xor(s, off);
  if (lane == 0) score[b] = s - log_norm[b];

  // backtrack: row loads are tag-independent -> prefetch 8 deep; only the
  // __shfl is on the dependent chain.
  __shared__ int sd[TT];
  const unsigned char* bpb = bp + (size_t)b * TT * UU;
  int tag = last_tag[b];
  if (lane == 0) sd[TT - 1] = tag;
#pragma unroll 1
  for (int tg = TT - 2; tg >= 0; tg -= 8) {
    unsigned char rows[8];
#pragma unroll
    for (int k = 0; k < 8; ++k) {
      int t = tg - k;
      rows[k] = (t >= 0) ? bpb[(size_t)t * UU + lane] : (unsigned char)0;
    }
#pragma unroll
    for (int k = 0; k < 8; ++k) {
      int t = tg - k;
      if (t >= 0) {
        int prev = __shfl((int)rows[k], tag);
        if (lane == 0) sd[t] = prev;
        tag = prev;
      }
    }
  }
  __syncthreads();
  float* db = dec_out + (size_t)b * TT;
#pragma unroll 1
  for (int i = 0; i < TT / 64; ++i) {
    int t = i * 64 + lane;
    db[t] = (t < len) ? (float)sd[t] : 0.f;
  }
}

// ---------------- final loss reduction ----------------
__global__ __launch_bounds__(128) void loss_kernel(
    const float* __restrict__ score, float* __restrict__ out)
{
  int tid = threadIdx.x;
  float s = score[tid];
#pragma unroll
  for (int off = 32; off > 0; off >>= 1)
    s += __shfl_xor(s, off);
  __shared__ float partial[2];
  if ((tid & 63) == 0) partial[tid >> 6] = s;
  __syncthreads();
  if (tid == 0) out[0] = -(partial[0] + partial[1]) / (float)BB;
}

extern "C" void kernel_launch(void* const* d_in, const int* in_sizes, int n_in,
                              void* d_out, int out_size, void* d_ws, size_t ws_size,
                              hipStream_t stream)
{
  (void)in_sizes; (void)n_in; (void)out_size;
  const float* x      = (const float*)d_in[0];
  const float* W      = (const float*)d_in[1];
  const float* bvec   = (const float*)d_in[2];
  const float* trans  = (const float*)d_in[3];
  const float* left   = (const float*)d_in[4];
  const float* right  = (const float*)d_in[5];
  const int* tags     = (const int*)d_in[6];
  const int* lengths  = (const int*)d_in[7];

  float* out      = (float*)d_out;
  float* dec_out  = out + 1;                       // [B,T] as float
  float* pot      = out + 1 + (size_t)BB * TT;     // [B,T,U]

  const size_t bpB = (size_t)BB * TT * UU;         // 8 MiB backpointers
  const size_t vaB = (size_t)BB * TT * UU * 4;     // 32 MiB viterbi alphas
  const int fast = (ws_size >= bpB + vaB + 4096) ? 1 : 0;

  unsigned char* bp = (unsigned char*)d_ws;
  float* valpha     = (float*)((char*)d_ws + bpB);
  char* tail        = (char*)d_ws + bpB + (fast ? vaB : 0);
  float* log_norm   = (float*)tail;
  int*   last_tag   = (int*)(log_norm + BB);
  float* score      = (float*)(last_tag + BB);

  pot_kernel<<<(BB * TT) / 64, 64, 0, stream>>>(x, W, bvec, left, right, lengths, pot);
  scan_kernel<<<2 * BB, 64, 0, stream>>>(pot, trans, lengths, bp, log_norm, last_tag, valpha, fast);
  if (fast)
    bp_kernel<<<BB * 64, 256, 0, stream>>>(valpha, trans, lengths, bp);
  decode_kernel<<<BB, 64, 0, stream>>>(pot, trans, tags, lengths, bp, log_norm, last_tag, score, dec_out);
  loss_kernel<<<1, 128, 0, stream>>>(score, out);
}